// Round 16
// baseline (640.751 us; speedup 1.0000x reference)
//
#include <hip/hip_runtime.h>

typedef __attribute__((ext_vector_type(8))) short short8;
typedef __attribute__((ext_vector_type(4))) float f32x4;
typedef unsigned short u16;
typedef unsigned int u32;

// round-to-nearest-even f32 -> bf16
__device__ __forceinline__ u16 f2bf(float f){
  union { float f; u32 u; } v; v.f = f;
  u32 u = v.u;
  u32 r = (u + 0x7FFFu + ((u >> 16) & 1u)) >> 16;
  return (u16)r;
}

// pack two f32 -> bf16x2 (RNE), S0 in low half
__device__ __forceinline__ u32 cvtpk(float a, float b){
  u32 r;
  asm("v_cvt_pk_bf16_f32 %0, %1, %2" : "=v"(r) : "v"(a), "v"(b));
  return r;
}

// XOR swizzle on byte-in-row (bits 4..6) to break power-of-2 row strides
__device__ __forceinline__ int swz(int row, int cb){ return cb ^ ((row & 7) << 4); }

// async global->LDS 16B copy (wave-uniform LDS base, lane-strided dest)
__device__ __forceinline__ void gload16(const void* g, void* l){
  __builtin_amdgcn_global_load_lds(
      (const __attribute__((address_space(1))) unsigned int*)g,
      (__attribute__((address_space(3))) unsigned int*)l, 16, 0, 0);
}

// ===========================================================================
// K0: weights -> FRAGMENT-MAJOR bf16 layouts (r7-verified).
// ===========================================================================
__global__ void convert_weights_frag(const float* __restrict__ wqkv,
                                     const float* __restrict__ wproj,
                                     u16* __restrict__ wqf,
                                     u16* __restrict__ wpf){
  int c = blockIdx.x * 256 + threadIdx.x;    // 131072 chunks total
  union { u16 u[8]; uint4 v; } t;
  if (c < 98304){
    int bn = c >> 13;
    int r  = c & 8191;
    int kt = r >> 10;
    int q  = r & 1023;
    int nsub = q >> 7;
    int ks = (q >> 6) & 1;
    int l  = q & 63;
    int e  = bn*128 + nsub*16 + (l & 15);
    int k0 = kt*64 + ks*32 + (l >> 4)*8;
    #pragma unroll
    for (int i = 0; i < 8; ++i) t.u[i] = f2bf(wqkv[(long)(k0 + i) * 1536 + e]);
    *reinterpret_cast<uint4*>(wqf + (long)c * 8) = t.v;
  } else {
    int c2 = c - 98304;
    int cb = c2 >> 12;
    int r  = c2 & 4095;
    int hh = r >> 9;
    int q  = r & 511;
    int n  = q >> 7;
    int ks = (q >> 6) & 1;
    int l  = q & 63;
    int e  = cb*64 + n*16 + (l & 15);
    int k0 = hh*64 + ks*32 + (l >> 4)*8;
    #pragma unroll
    for (int i = 0; i < 8; ++i) t.u[i] = f2bf(wproj[(long)(k0 + i) * 512 + e]);
    *reinterpret_cast<uint4*>(wpf + (long)c2 * 8) = t.v;
  }
}

// ===========================================================================
// K0b: x f32 -> bf16 pre-swizzled 128x64 tiles (A half-tiles).
// ===========================================================================
__global__ void convert_x(const float* __restrict__ x, u16* __restrict__ xbf){
  int c = blockIdx.x * 256 + threadIdx.x;
  int tile = c >> 10, row = (c >> 3) & 127, c7 = c & 7;
  int bm = tile >> 3, kt = tile & 7;
  int j  = c7 ^ (row & 7);
  const float* src = x + (long)(bm * 128 + row) * 512 + kt * 64 + j * 8;
  float4 v0 = *reinterpret_cast<const float4*>(src);
  float4 v1 = *reinterpret_cast<const float4*>(src + 4);
  union { u16 u[8]; uint4 v; } t;
  t.u[0] = f2bf(v0.x); t.u[1] = f2bf(v0.y); t.u[2] = f2bf(v0.z); t.u[3] = f2bf(v0.w);
  t.u[4] = f2bf(v1.x); t.u[5] = f2bf(v1.y); t.u[6] = f2bf(v1.z); t.u[7] = f2bf(v1.w);
  *reinterpret_cast<uint4*>(xbf + (long)c * 8) = t.v;
}

// ===========================================================================
// K1 v9: r7 structure + B-REGISTER DOUBLE BUFFER. A via global_load_lds
// ring (2-deep), B frag-major from global loaded ONE TILE AHEAD so the
// 32-MFMA cluster covers its L2 latency. Counted vmcnt(12)/(8); no other
// changes vs the verified r7 kernel.
// ===========================================================================
__global__ __launch_bounds__(256, 3) void qkv_gemm128(
    const u16*  __restrict__ xbf,
    const u16*  __restrict__ wqf,
    const float* __restrict__ bqkv,
    u16* __restrict__ qkv)
{
  __shared__ char smem[34816];   // ring 2x16KB; epilogue [128][136] u16

  const int tid = threadIdx.x;
  const int l = tid & 63, w = tid >> 6;
  const int g = l >> 4,  ln = l & 15;
  const int wm = w >> 1, wn = w & 1;

  // XCD-chunked remap: 12288 blocks, 1536/XCD; 12 n-blocks share an A-panel
  int hb   = blockIdx.x;
  int work = (hb & 7) * 1536 + (hb >> 3);
  int bn   = work % 12;
  int bm   = work / 12;

  f32x4 acc[4][4];
  #pragma unroll
  for (int m = 0; m < 4; ++m)
    #pragma unroll
    for (int n = 0; n < 4; ++n) acc[m][n] = (f32x4){0.f,0.f,0.f,0.f};

  const char* abase = (const char*)(xbf + (long)(bm * 8) * 8192);
  const u16*  bbase = wqf + (long)bn * 65536;

  auto stageA = [&](int kt, int slot){
    const char* src = abase + (long)kt * 16384;
    char* dst = smem + slot * 16384;
    #pragma unroll
    for (int i = 0; i < 4; ++i)
      gload16(src + (i*256 + tid)*16, dst + i*4096 + w*1024);
  };
  auto loadB = [&](int t, short8 (&b)[4][2]){
    #pragma unroll
    for (int n = 0; n < 4; ++n)
      #pragma unroll
      for (int ks = 0; ks < 2; ++ks)
        b[n][ks] = *reinterpret_cast<const short8*>(
            bbase + ((((long)t*8 + wn*4 + n)*2 + ks)*64 + l)*8);
  };

  short8 b0[4][2], b1[4][2];

  // prologue: A(0),A(1) staged; b(0) in flight; wait A(0) only (vmcnt leaves
  // stage(1)[4]+b(0)[8] = 12 in flight)
  stageA(0, 0); stageA(1, 1);
  loadB(0, b0);
  asm volatile("s_waitcnt vmcnt(12)" ::: "memory");
  __builtin_amdgcn_s_barrier();

  auto body = [&](int t, short8 (&bcur)[4][2], short8 (&bnext)[4][2]){
    // A(t) frags from LDS ring
    const char* Ab = smem + (t & 1) * 16384;
    short8 a[4][2];
    #pragma unroll
    for (int m = 0; m < 4; ++m){
      int r = wm*64 + m*16 + ln;
      #pragma unroll
      for (int ks = 0; ks < 2; ++ks)
        a[m][ks] = *reinterpret_cast<const short8*>(
            Ab + r*128 + (((ks*4 + g) ^ (r & 7)) << 4));
    }
    asm volatile("s_waitcnt lgkmcnt(0)" ::: "memory");
    __builtin_amdgcn_s_barrier();                 // slot (t&1) fully consumed
    if (t < 6) stageA(t + 2, t & 1);              // refill the freed slot
    if (t < 7) loadB(t + 1, bnext);               // B one tile ahead
    __builtin_amdgcn_s_setprio(1);
    #pragma unroll
    for (int m = 0; m < 4; ++m)
      #pragma unroll
      for (int n = 0; n < 4; ++n)
        #pragma unroll
        for (int ks = 0; ks < 2; ++ks)
          acc[m][n] = __builtin_amdgcn_mfma_f32_16x16x32_bf16(
              a[m][ks], bcur[n][ks], acc[m][n], 0, 0, 0);
    __builtin_amdgcn_s_setprio(0);
    // counted wait: drain stage(t+1)+b(t); keep stage(t+2)[4]+b(t+1)[8]
    if (t < 6)       asm volatile("s_waitcnt vmcnt(12)" ::: "memory");
    else if (t == 6) asm volatile("s_waitcnt vmcnt(8)"  ::: "memory");
    if (t < 7) __builtin_amdgcn_s_barrier();
  };

  #pragma unroll
  for (int tt = 0; tt < 4; ++tt){
    body(2*tt,     b0, b1);
    body(2*tt + 1, b1, b0);
  }

  // epilogue: bias + bf16 via LDS roundtrip, coalesced 128B rows
  u16* ldsC = (u16*)smem;
  #pragma unroll
  for (int n = 0; n < 4; ++n){
    int col  = wn*64 + n*16 + ln;
    float bias = bqkv[bn*128 + col];
    #pragma unroll
    for (int m = 0; m < 4; ++m){
      int r0 = wm*64 + m*16 + g*4;
      #pragma unroll
      for (int r = 0; r < 4; ++r)
        ldsC[(r0 + r) * 136 + col] = f2bf(acc[m][n][r] + bias);
    }
  }
  __syncthreads();
  {
    int row = tid >> 1, half = tid & 1;
    const char* src = (const char*)(ldsC + row * 136 + half * 64);
    char* dst = (char*)qkv + ((long)(bm*128 + row) * 1536 + bn*128 + half*64) * 2;
    #pragma unroll
    for (int j = 0; j < 8; ++j)
      *reinterpret_cast<uint4*>(dst + j*16) = *reinterpret_cast<const uint4*>(src + j*16);
  }
}

// ===========================================================================
// K2 (r7-verified): fused window attention + projection.
// ===========================================================================
__global__ __launch_bounds__(512, 4) void winattn_proj(
    const u16* __restrict__ qkv,
    const u16* __restrict__ wpf,
    const float* __restrict__ bproj,
    float* __restrict__ out)
{
  __shared__ u16 lds[8][4096];   // per wave: V^T then O (swizzled, 128B rows)
  const int tid = threadIdx.x;
  const int l = tid & 63, w = tid >> 6;
  const int g = l >> 4,  ln = l & 15;
  const int gh = g >> 1, gl = g & 1;
  const long tokb = (long)blockIdx.x * 64;
  u16* vt = lds[w];
  const int h = w;

  // ---- V rows -> swizzled V^T in LDS (wave-private) ----
  {
    const int dg = l & 3, tg = l >> 2;
    uint4 vr[4][2];
    #pragma unroll
    for (int r = 0; r < 4; ++r){
      const char* vrow = (const char*)(qkv + (tokb + tg*4 + r) * 1536 + 1024 + h*64 + dg*16);
      vr[r][0] = *reinterpret_cast<const uint4*>(vrow);
      vr[r][1] = *reinterpret_cast<const uint4*>(vrow + 16);
    }
    #pragma unroll
    for (int dd = 0; dd < 16; ++dd){
      int d = dg*16 + dd;
      int sub = dd & 7, hi = dd >> 3;
      uint2 pk;
      pk.x = (u32)((const u16*)&vr[0][hi])[sub] | ((u32)((const u16*)&vr[1][hi])[sub] << 16);
      pk.y = (u32)((const u16*)&vr[2][hi])[sub] | ((u32)((const u16*)&vr[3][hi])[sub] << 16);
      *reinterpret_cast<uint2*>((char*)vt + d*128 + swz(d, tg*8)) = pk;
    }
  }

  f32x4 oacc[4][4];
  #pragma unroll
  for (int m = 0; m < 4; ++m)
    #pragma unroll
    for (int n = 0; n < 4; ++n) oacc[m][n] = (f32x4){0.f,0.f,0.f,0.f};

  const int lnA = ln + 32*gl;

  #pragma unroll
  for (int half = 0; half < 2; ++half){
    short8 qa[2][2];
    #pragma unroll
    for (int j = 0; j < 2; ++j){
      const char* qrow = (const char*)(qkv + (tokb + (half*2+j)*16 + ln) * 1536 + h*64 + g*8);
      qa[j][0] = *reinterpret_cast<const short8*>(qrow);
      qa[j][1] = *reinterpret_cast<const short8*>(qrow + 64);
    }
    f32x4 st[4][2];
    #pragma unroll
    for (int mk = 0; mk < 4; ++mk){
      st[mk][0] = (f32x4){0.f,0.f,0.f,0.f};
      st[mk][1] = (f32x4){0.f,0.f,0.f,0.f};
    }
    #pragma unroll
    for (int mk = 0; mk < 4; ++mk){
      const char* krow = (const char*)(qkv + (tokb + mk*16 + ln) * 1536 + 512 + h*64 + g*8);
      short8 kb0 = *reinterpret_cast<const short8*>(krow);
      short8 kb1 = *reinterpret_cast<const short8*>(krow + 64);
      #pragma unroll
      for (int j = 0; j < 2; ++j){
        st[mk][j] = __builtin_amdgcn_mfma_f32_16x16x32_bf16(kb0, qa[j][0], st[mk][j], 0, 0, 0);
        st[mk][j] = __builtin_amdgcn_mfma_f32_16x16x32_bf16(kb1, qa[j][1], st[mk][j], 0, 0, 0);
      }
    }
    u32 warr[4][2][2];
    #pragma unroll
    for (int j = 0; j < 2; ++j){
      float mx = -3.4e38f;
      #pragma unroll
      for (int mk = 0; mk < 4; ++mk)
        #pragma unroll
        for (int r = 0; r < 4; ++r) mx = fmaxf(mx, st[mk][j][r]);
      mx = fmaxf(mx, __shfl_xor(mx, 16, 64));
      mx = fmaxf(mx, __shfl_xor(mx, 32, 64));
      float s = 0.f;
      #pragma unroll
      for (int mk = 0; mk < 4; ++mk)
        #pragma unroll
        for (int r = 0; r < 4; ++r){
          float p = __expf((st[mk][j][r] - mx) * 0.125f);
          st[mk][j][r] = p; s += p;
        }
      s += __shfl_xor(s, 16, 64);
      s += __shfl_xor(s, 32, 64);
      float inv = 1.f / s;
      #pragma unroll
      for (int mk = 0; mk < 4; ++mk){
        warr[mk][j][0] = cvtpk(st[mk][j][0]*inv, st[mk][j][1]*inv);
        warr[mk][j][1] = cvtpk(st[mk][j][2]*inv, st[mk][j][3]*inv);
      }
    }
    __builtin_amdgcn_s_setprio(1);
    #pragma unroll
    for (int ks = 0; ks < 2; ++ks){
      short8 vb[4];
      #pragma unroll
      for (int n = 0; n < 4; ++n){
        int row = n*16 + ln;
        vb[n] = *reinterpret_cast<const short8*>((char*)vt + row*128 + swz(row, (ks*32 + g*8)*2));
      }
      #pragma unroll
      for (int mo = 0; mo < 2; ++mo){
        int m = half*2 + mo;
        u32 c0a = warr[2*ks  ][mo][0], c0b = warr[2*ks  ][mo][1];
        u32 c1a = warr[2*ks+1][mo][0], c1b = warr[2*ks+1][mo][1];
        u32 s0a = (u32)__shfl((int)c0a, lnA, 64);
        u32 s1a = (u32)__shfl((int)c1a, lnA, 64);
        u32 s0b = (u32)__shfl((int)c0b, lnA, 64);
        u32 s1b = (u32)__shfl((int)c1b, lnA, 64);
        u32 t0a = (u32)__shfl((int)c0a, lnA+16, 64);
        u32 t1a = (u32)__shfl((int)c1a, lnA+16, 64);
        u32 t0b = (u32)__shfl((int)c0b, lnA+16, 64);
        u32 t1b = (u32)__shfl((int)c1b, lnA+16, 64);
        union { u32 u[4]; short8 v; } pf;
        pf.u[0] = gh ? s1a : s0a;
        pf.u[1] = gh ? s1b : s0b;
        pf.u[2] = gh ? t1a : t0a;
        pf.u[3] = gh ? t1b : t0b;
        #pragma unroll
        for (int n = 0; n < 4; ++n)
          oacc[m][n] = __builtin_amdgcn_mfma_f32_16x16x32_bf16(pf.v, vb[n], oacc[m][n], 0, 0, 0);
      }
    }
    __builtin_amdgcn_s_setprio(0);
  }

  #pragma unroll
  for (int m = 0; m < 4; ++m)
    #pragma unroll
    for (int n = 0; n < 4; ++n){
      int d = n*16 + ln;
      #pragma unroll
      for (int r = 0; r < 4; ++r){
        int t = m*16 + g*4 + r;
        *reinterpret_cast<u16*>((char*)vt + t*128 + swz(t, d*2)) = f2bf(oacc[m][n][r]);
      }
    }

  __syncthreads();

  f32x4 acc[4][4];
  #pragma unroll
  for (int m = 0; m < 4; ++m)
    #pragma unroll
    for (int n = 0; n < 4; ++n) acc[m][n] = (f32x4){0.f,0.f,0.f,0.f};

  for (int hh = 0; hh < 8; ++hh){
    const char* obuf = (const char*)lds[hh];
    #pragma unroll
    for (int ks = 0; ks < 2; ++ks){
      short8 a[4], b[4];
      #pragma unroll
      for (int m = 0; m < 4; ++m){
        int row = m*16 + ln;
        a[m] = *reinterpret_cast<const short8*>(obuf + row*128 + swz(row, (ks*32 + g*8)*2));
      }
      #pragma unroll
      for (int n = 0; n < 4; ++n)
        b[n] = *reinterpret_cast<const short8*>(
            wpf + ((((long)w*8 + hh)*4 + n)*2 + ks)*512 + (long)l*8);
      __builtin_amdgcn_s_setprio(1);
      #pragma unroll
      for (int m = 0; m < 4; ++m)
        #pragma unroll
        for (int n = 0; n < 4; ++n)
          acc[m][n] = __builtin_amdgcn_mfma_f32_16x16x32_bf16(a[m], b[n], acc[m][n], 0, 0, 0);
      __builtin_amdgcn_s_setprio(0);
    }
  }

  #pragma unroll
  for (int n = 0; n < 4; ++n){
    int col = w*64 + n*16 + ln;
    float bias = bproj[col];
    #pragma unroll
    for (int m = 0; m < 4; ++m){
      #pragma unroll
      for (int r = 0; r < 4; ++r){
        int t = m*16 + g*4 + r;
        out[(tokb + t) * 512 + col] = acc[m][n][r] + bias;
      }
    }
  }
}

// ===========================================================================
// Fallback (round-1 fused kernel) for small ws_size
// ===========================================================================
__global__ void convert_weights(const float* __restrict__ wqkv,
                                const float* __restrict__ wproj,
                                u16* __restrict__ wqkvt,
                                u16* __restrict__ wprojt){
  int tid = blockIdx.x * 256 + threadIdx.x;
  union { u16 u[8]; uint4 v; } tmp;
  if (tid < 1536 * 64){
    int e  = tid >> 6;
    int kc = (tid & 63) << 3;
    #pragma unroll
    for (int i = 0; i < 8; ++i) tmp.u[i] = f2bf(wqkv[(long)(kc + i) * 1536 + e]);
    *reinterpret_cast<uint4*>(wqkvt + (long)e * 512 + kc) = tmp.v;
  } else {
    int t2 = tid - 1536 * 64;
    int c  = t2 >> 6;
    int kc = (t2 & 63) << 3;
    #pragma unroll
    for (int i = 0; i < 8; ++i) tmp.u[i] = f2bf(wproj[(long)(kc + i) * 512 + c]);
    *reinterpret_cast<uint4*>(wprojt + (long)c * 512 + kc) = tmp.v;
  }
}

__global__ __launch_bounds__(512, 2) void fused_winattn(
    const float* __restrict__ x,
    const u16*  __restrict__ wqkvt,
    const float* __restrict__ bqkv,
    const u16*  __restrict__ wprojt,
    const float* __restrict__ bproj,
    float* __restrict__ out)
{
  __shared__ u16 lds_x[64 * 512];
  __shared__ u16 lds_q[64 * 64];
  __shared__ u16 lds_k[64 * 64];
  __shared__ u16 lds_vt[64 * 64];
  __shared__ u16 lds_p[64 * 64];

  const int tid = threadIdx.x;
  const int l   = tid & 63;
  const int w   = tid >> 6;
  const int g   = l >> 4;
  const int ln  = l & 15;
  const long tokbase = (long)blockIdx.x * 64;

  {
    const float4* xv = reinterpret_cast<const float4*>(x + tokbase * 512);
    #pragma unroll
    for (int j = 0; j < 16; ++j){
      int i   = j * 512 + tid;
      int row = i >> 7;
      int c4  = i & 127;
      float4 v = xv[i];
      uint2 pk;
      pk.x = (u32)f2bf(v.x) | ((u32)f2bf(v.y) << 16);
      pk.y = (u32)f2bf(v.z) | ((u32)f2bf(v.w) << 16);
      int byte = row * 1024 + swz(row, c4 * 8);
      *reinterpret_cast<uint2*>(reinterpret_cast<char*>(lds_x) + byte) = pk;
    }
  }

  f32x4 oacc[4][4];
  #pragma unroll
  for (int m = 0; m < 4; ++m)
    #pragma unroll
    for (int n = 0; n < 4; ++n) oacc[m][n] = (f32x4){0.f, 0.f, 0.f, 0.f};

  const int mw   = w & 3;
  const int half = w >> 2;

  __syncthreads();

  for (int h = 0; h < 8; ++h){
    f32x4 qacc[6];
    #pragma unroll
    for (int j = 0; j < 6; ++j) qacc[j] = (f32x4){0.f, 0.f, 0.f, 0.f};
    int ebase[6];
    #pragma unroll
    for (int j = 0; j < 6; ++j){
      int nt = half * 6 + j;
      int sec = nt >> 2;
      ebase[j] = sec * 512 + h * 64 + (nt & 3) * 16;
    }
    const int arow = mw * 16 + ln;
    #pragma unroll
    for (int ks = 0; ks < 16; ++ks){
      short8 a = *reinterpret_cast<const short8*>(
          reinterpret_cast<const char*>(lds_x) + arow * 1024 + swz(arow, (ks * 32 + g * 8) * 2));
      #pragma unroll
      for (int j = 0; j < 6; ++j){
        short8 b = *reinterpret_cast<const short8*>(
            wqkvt + (long)(ebase[j] + ln) * 512 + ks * 32 + g * 8);
        qacc[j] = __builtin_amdgcn_mfma_f32_16x16x32_bf16(a, b, qacc[j], 0, 0, 0);
      }
    }
    #pragma unroll
    for (int j = 0; j < 6; ++j){
      int nt  = half * 6 + j;
      int sec = nt >> 2;
      float bias = bqkv[ebase[j] + ln];
      if (sec < 2){
        u16* dst = (sec == 0) ? lds_q : lds_k;
        int c = (nt & 3) * 16 + ln;
        #pragma unroll
        for (int r = 0; r < 4; ++r){
          int t = mw * 16 + g * 4 + r;
          int byte = t * 128 + swz(t, c * 2);
          *reinterpret_cast<u16*>(reinterpret_cast<char*>(dst) + byte) = f2bf(qacc[j][r] + bias);
        }
      } else {
        int d  = (nt & 3) * 16 + ln;
        int t0 = mw * 16 + g * 4;
        uint2 pk;
        pk.x = (u32)f2bf(qacc[j][0] + bias) | ((u32)f2bf(qacc[j][1] + bias) << 16);
        pk.y = (u32)f2bf(qacc[j][2] + bias) | ((u32)f2bf(qacc[j][3] + bias) << 16);
        int byte = d * 128 + swz(d, t0 * 2);
        *reinterpret_cast<uint2*>(reinterpret_cast<char*>(lds_vt) + byte) = pk;
      }
    }
    __syncthreads();

    if (w < 4){
      f32x4 sacc[4];
      #pragma unroll
      for (int jt = 0; jt < 4; ++jt) sacc[jt] = (f32x4){0.f, 0.f, 0.f, 0.f};
      #pragma unroll
      for (int ks = 0; ks < 2; ++ks){
        int qrow = w * 16 + ln;
        short8 a = *reinterpret_cast<const short8*>(
            reinterpret_cast<const char*>(lds_q) + qrow * 128 + swz(qrow, (ks * 32 + g * 8) * 2));
        #pragma unroll
        for (int jt = 0; jt < 4; ++jt){
          int krow = jt * 16 + ln;
          short8 b = *reinterpret_cast<const short8*>(
              reinterpret_cast<const char*>(lds_k) + krow * 128 + swz(krow, (ks * 32 + g * 8) * 2));
          sacc[jt] = __builtin_amdgcn_mfma_f32_16x16x32_bf16(a, b, sacc[jt], 0, 0, 0);
        }
      }
      #pragma unroll
      for (int r = 0; r < 4; ++r){
        float mx = fmaxf(fmaxf(sacc[0][r], sacc[1][r]), fmaxf(sacc[2][r], sacc[3][r]));
        mx = fmaxf(mx, __shfl_xor(mx, 1, 64));
        mx = fmaxf(mx, __shfl_xor(mx, 2, 64));
        mx = fmaxf(mx, __shfl_xor(mx, 4, 64));
        mx = fmaxf(mx, __shfl_xor(mx, 8, 64));
        float p[4], s = 0.f;
        #pragma unroll
        for (int jt = 0; jt < 4; ++jt){
          p[jt] = __expf((sacc[jt][r] - mx) * 0.125f);
          s += p[jt];
        }
        s += __shfl_xor(s, 1, 64);
        s += __shfl_xor(s, 2, 64);
        s += __shfl_xor(s, 4, 64);
        s += __shfl_xor(s, 8, 64);
        float inv = 1.f / s;
        int i = w * 16 + g * 4 + r;
        #pragma unroll
        for (int jt = 0; jt < 4; ++jt){
          int c = jt * 16 + ln;
          int byte = i * 128 + swz(i, c * 2);
          *reinterpret_cast<u16*>(reinterpret_cast<char*>(lds_p) + byte) = f2bf(p[jt] * inv);
        }
      }
    }
    __syncthreads();

    {
      int mc  = w & 3;
      int nc0 = (w >> 2) * 2;
      f32x4 oc[2];
      oc[0] = (f32x4){0.f, 0.f, 0.f, 0.f};
      oc[1] = (f32x4){0.f, 0.f, 0.f, 0.f};
      #pragma unroll
      for (int ks = 0; ks < 2; ++ks){
        int prow = mc * 16 + ln;
        short8 a = *reinterpret_cast<const short8*>(
            reinterpret_cast<const char*>(lds_p) + prow * 128 + swz(prow, (ks * 32 + g * 8) * 2));
        #pragma unroll
        for (int jj = 0; jj < 2; ++jj){
          int vrow = (nc0 + jj) * 16 + ln;
          short8 b = *reinterpret_cast<const short8*>(
              reinterpret_cast<const char*>(lds_vt) + vrow * 128 + swz(vrow, (ks * 32 + g * 8) * 2));
          oc[jj] = __builtin_amdgcn_mfma_f32_16x16x32_bf16(a, b, oc[jj], 0, 0, 0);
        }
      }
      #pragma unroll
      for (int jj = 0; jj < 2; ++jj){
        int d = (nc0 + jj) * 16 + ln;
        #pragma unroll
        for (int r = 0; r < 4; ++r){
          int t = mc * 16 + g * 4 + r;
          int byte = t * 128 + swz(t, d * 2);
          *reinterpret_cast<u16*>(reinterpret_cast<char*>(lds_q) + byte) = f2bf(oc[jj][r]);
        }
      }
    }
    __syncthreads();

    #pragma unroll
    for (int ks = 0; ks < 2; ++ks){
      short8 a[4];
      #pragma unroll
      for (int m = 0; m < 4; ++m){
        int row = m * 16 + ln;
        a[m] = *reinterpret_cast<const short8*>(
            reinterpret_cast<const char*>(lds_q) + row * 128 + swz(row, (ks * 32 + g * 8) * 2));
      }
      #pragma unroll
      for (int nt = 0; nt < 4; ++nt){
        int e = w * 64 + nt * 16 + ln;
        short8 b = *reinterpret_cast<const short8*>(
            wprojt + (long)e * 512 + h * 64 + ks * 32 + g * 8);
        #pragma unroll
        for (int m = 0; m < 4; ++m)
          oacc[m][nt] = __builtin_amdgcn_mfma_f32_16x16x32_bf16(a[m], b, oacc[m][nt], 0, 0, 0);
      }
    }
    __syncthreads();
  }

  #pragma unroll
  for (int nt = 0; nt < 4; ++nt){
    int col = w * 64 + nt * 16 + ln;
    float bias = bproj[col];
    #pragma unroll
    for (int m = 0; m < 4; ++m){
      #pragma unroll
      for (int r = 0; r < 4; ++r){
        int t = m * 16 + g * 4 + r;
        out[(tokbase + t) * 512 + col] = oacc[m][nt][r] + bias;
      }
    }
  }
}

extern "C" void kernel_launch(void* const* d_in, const int* in_sizes, int n_in,
                              void* d_out, int out_size, void* d_ws, size_t ws_size,
                              hipStream_t stream) {
  const float* x     = (const float*)d_in[0];
  const float* wqkv  = (const float*)d_in[1];
  const float* bqkv  = (const float*)d_in[2];
  const float* wproj = (const float*)d_in[3];
  const float* bproj = (const float*)d_in[4];
  float* out = (float*)d_out;

  // wqf 1.5M + wpf 0.5M + xbf 128M + qkv 384M = 514 MiB
  const size_t NEED = 538968064ULL;
  if (ws_size >= NEED){
    u16* wqf = (u16*)d_ws;
    u16* wpf = (u16*)((char*)d_ws + 1572864);
    u16* xbf = (u16*)((char*)d_ws + 2097152);
    u16* qkv = (u16*)((char*)d_ws + 136314880);
    convert_weights_frag<<<512, 256, 0, stream>>>(wqkv, wproj, wqf, wpf);
    convert_x<<<32768, 256, 0, stream>>>(x, xbf);
    qkv_gemm128<<<12288, 256, 0, stream>>>(xbf, wqf, bqkv, qkv);
    winattn_proj<<<2048, 512, 0, stream>>>(qkv, wpf, bproj, out);
  } else {
    u16* wqkvt  = (u16*)d_ws;
    u16* wprojt = wqkvt + 1536 * 512;
    convert_weights<<<512, 256, 0, stream>>>(wqkv, wproj, wqkvt, wprojt);
    fused_winattn<<<2048, 512, 0, stream>>>(x, wqkvt, bqkv, wprojt, bproj, out);
  }
}

// Round 17
// 582.328 us; speedup vs baseline: 1.1003x; 1.1003x over previous
//
#include <hip/hip_runtime.h>

typedef __attribute__((ext_vector_type(8))) short short8;
typedef __attribute__((ext_vector_type(4))) float f32x4;
typedef unsigned short u16;
typedef unsigned int u32;

// round-to-nearest-even f32 -> bf16
__device__ __forceinline__ u16 f2bf(float f){
  union { float f; u32 u; } v; v.f = f;
  u32 u = v.u;
  u32 r = (u + 0x7FFFu + ((u >> 16) & 1u)) >> 16;
  return (u16)r;
}

// pack two f32 -> bf16x2 (RNE), S0 in low half
__device__ __forceinline__ u32 cvtpk(float a, float b){
  u32 r;
  asm("v_cvt_pk_bf16_f32 %0, %1, %2" : "=v"(r) : "v"(a), "v"(b));
  return r;
}

// XOR swizzle on byte-in-row (bits 4..6) to break power-of-2 row strides
__device__ __forceinline__ int swz(int row, int cb){ return cb ^ ((row & 7) << 4); }

// async global->LDS 16B copy (wave-uniform LDS base, lane-strided dest)
__device__ __forceinline__ void gload16(const void* g, void* l){
  __builtin_amdgcn_global_load_lds(
      (const __attribute__((address_space(1))) unsigned int*)g,
      (__attribute__((address_space(3))) unsigned int*)l, 16, 0, 0);
}

// ===========================================================================
// K0: weights -> FRAGMENT-MAJOR bf16 layouts (r7-verified).
// wqf chunks [bn:12][kt:8][nsub:8][ks:2][l:64] : 16B chunk (l) holds
//   wqkv^T[e = bn*128+nsub*16+(l&15)][k = kt*64+ks*32+(l>>4)*8 .. +8)
// wpf chunks [cb:8][hh:8][n:4][ks:2][l:64] :
//   wproj^T[e = cb*64+n*16+(l&15)][k = hh*64+ks*32+(l>>4)*8 .. +8)
// ===========================================================================
__global__ void convert_weights_frag(const float* __restrict__ wqkv,
                                     const float* __restrict__ wproj,
                                     u16* __restrict__ wqf,
                                     u16* __restrict__ wpf){
  int c = blockIdx.x * 256 + threadIdx.x;    // 131072 chunks total
  union { u16 u[8]; uint4 v; } t;
  if (c < 98304){
    int bn = c >> 13;
    int r  = c & 8191;
    int kt = r >> 10;
    int q  = r & 1023;
    int nsub = q >> 7;
    int ks = (q >> 6) & 1;
    int l  = q & 63;
    int e  = bn*128 + nsub*16 + (l & 15);
    int k0 = kt*64 + ks*32 + (l >> 4)*8;
    #pragma unroll
    for (int i = 0; i < 8; ++i) t.u[i] = f2bf(wqkv[(long)(k0 + i) * 1536 + e]);
    *reinterpret_cast<uint4*>(wqf + (long)c * 8) = t.v;
  } else {
    int c2 = c - 98304;
    int cb = c2 >> 12;
    int r  = c2 & 4095;
    int hh = r >> 9;
    int q  = r & 511;
    int n  = q >> 7;
    int ks = (q >> 6) & 1;
    int l  = q & 63;
    int e  = cb*64 + n*16 + (l & 15);
    int k0 = hh*64 + ks*32 + (l >> 4)*8;
    #pragma unroll
    for (int i = 0; i < 8; ++i) t.u[i] = f2bf(wproj[(long)(k0 + i) * 512 + e]);
    *reinterpret_cast<uint4*>(wpf + (long)c2 * 8) = t.v;
  }
}

// ===========================================================================
// K0b: x f32 -> bf16 pre-swizzled 128x64 tiles (A half-tiles).
// ===========================================================================
__global__ void convert_x(const float* __restrict__ x, u16* __restrict__ xbf){
  int c = blockIdx.x * 256 + threadIdx.x;
  int tile = c >> 10, row = (c >> 3) & 127, c7 = c & 7;
  int bm = tile >> 3, kt = tile & 7;
  int j  = c7 ^ (row & 7);
  const float* src = x + (long)(bm * 128 + row) * 512 + kt * 64 + j * 8;
  float4 v0 = *reinterpret_cast<const float4*>(src);
  float4 v1 = *reinterpret_cast<const float4*>(src + 4);
  union { u16 u[8]; uint4 v; } t;
  t.u[0] = f2bf(v0.x); t.u[1] = f2bf(v0.y); t.u[2] = f2bf(v0.z); t.u[3] = f2bf(v0.w);
  t.u[4] = f2bf(v1.x); t.u[5] = f2bf(v1.y); t.u[6] = f2bf(v1.z); t.u[7] = f2bf(v1.w);
  *reinterpret_cast<uint4*>(xbf + (long)c * 8) = t.v;
}

// ===========================================================================
// K1 (r7-verified, 325us): QKV GEMM, 128x128 tile, BK=64, 4 waves (2Mx2N),
// A-only LDS (2x16KB ring) via global_load_lds from pre-swizzled tiles,
// B fragments DIRECT from global (frag-major, 1KB coalesced per wave-load,
// L2-resident). 3 blocks/CU. Counted vmcnt(4), 2-deep A prefetch.
// ===========================================================================
__global__ __launch_bounds__(256, 3) void qkv_gemm128(
    const u16*  __restrict__ xbf,
    const u16*  __restrict__ wqf,
    const float* __restrict__ bqkv,
    u16* __restrict__ qkv)
{
  __shared__ char smem[34816];   // ring 2x16KB; epilogue [128][136] u16

  const int tid = threadIdx.x;
  const int l = tid & 63, w = tid >> 6;
  const int g = l >> 4,  ln = l & 15;
  const int wm = w >> 1, wn = w & 1;

  // XCD-chunked remap: 12288 blocks, 1536/XCD; 12 n-blocks share an A-panel
  int hb   = blockIdx.x;
  int work = (hb & 7) * 1536 + (hb >> 3);
  int bn   = work % 12;
  int bm   = work / 12;

  f32x4 acc[4][4];
  #pragma unroll
  for (int m = 0; m < 4; ++m)
    #pragma unroll
    for (int n = 0; n < 4; ++n) acc[m][n] = (f32x4){0.f,0.f,0.f,0.f};

  const char* abase = (const char*)(xbf + (long)(bm * 8) * 8192);
  const u16*  bbase = wqf + (long)bn * 65536;

  auto stageA = [&](int kt, int slot){
    const char* src = abase + (long)kt * 16384;
    char* dst = smem + slot * 16384;
    #pragma unroll
    for (int i = 0; i < 4; ++i)
      gload16(src + (i*256 + tid)*16, dst + i*4096 + w*1024);
  };

  stageA(0, 0); stageA(1, 1);
  asm volatile("s_waitcnt vmcnt(4)" ::: "memory");
  __builtin_amdgcn_s_barrier();

  for (int t = 0; t < 8; ++t){
    // B frags direct from global (coalesced 1KB per wave-load)
    short8 b[4][2];
    #pragma unroll
    for (int n = 0; n < 4; ++n)
      #pragma unroll
      for (int ks = 0; ks < 2; ++ks)
        b[n][ks] = *reinterpret_cast<const short8*>(
            bbase + ((((long)t*8 + wn*4 + n)*2 + ks)*64 + l)*8);
    // A frags from LDS ring
    const char* Ab = smem + (t & 1) * 16384;
    short8 a[4][2];
    #pragma unroll
    for (int m = 0; m < 4; ++m){
      int r = wm*64 + m*16 + ln;
      #pragma unroll
      for (int ks = 0; ks < 2; ++ks)
        a[m][ks] = *reinterpret_cast<const short8*>(
            Ab + r*128 + (((ks*4 + g) ^ (r & 7)) << 4));
    }
    asm volatile("s_waitcnt lgkmcnt(0)" ::: "memory");
    __builtin_amdgcn_s_barrier();                 // slot (t&1) fully consumed
    if (t < 6) stageA(t + 2, t & 1);              // refill the freed slot
    __builtin_amdgcn_s_setprio(1);
    #pragma unroll
    for (int m = 0; m < 4; ++m)
      #pragma unroll
      for (int n = 0; n < 4; ++n)
        #pragma unroll
        for (int ks = 0; ks < 2; ++ks)
          acc[m][n] = __builtin_amdgcn_mfma_f32_16x16x32_bf16(
              a[m][ks], b[n][ks], acc[m][n], 0, 0, 0);
    __builtin_amdgcn_s_setprio(0);
    // counted wait: ensure slot for t+1 landed; keep t+2 stage in flight
    if (t < 6)       asm volatile("s_waitcnt vmcnt(4)" ::: "memory");
    else if (t == 6) asm volatile("s_waitcnt vmcnt(0)" ::: "memory");
    if (t < 7) __builtin_amdgcn_s_barrier();
  }

  // epilogue: bias + bf16 via LDS roundtrip, coalesced 128B rows
  u16* ldsC = (u16*)smem;
  #pragma unroll
  for (int n = 0; n < 4; ++n){
    int col  = wn*64 + n*16 + ln;
    float bias = bqkv[bn*128 + col];
    #pragma unroll
    for (int m = 0; m < 4; ++m){
      int r0 = wm*64 + m*16 + g*4;
      #pragma unroll
      for (int r = 0; r < 4; ++r)
        ldsC[(r0 + r) * 136 + col] = f2bf(acc[m][n][r] + bias);
    }
  }
  __syncthreads();
  {
    int row = tid >> 1, half = tid & 1;
    const char* src = (const char*)(ldsC + row * 136 + half * 64);
    char* dst = (char*)qkv + ((long)(bm*128 + row) * 1536 + bn*128 + half*64) * 2;
    #pragma unroll
    for (int j = 0; j < 8; ++j)
      *reinterpret_cast<uint4*>(dst + j*16) = *reinterpret_cast<const uint4*>(src + j*16);
  }
}

// ===========================================================================
// K2 (r7-verified): fused window attention + projection. Wave = head;
// swapped QK^T, in-register softmax, cvtpk+shfl P, V^T in wave LDS slot,
// O overwrites slot, one barrier, per-wave 64-col proj slice (wpf frag-major).
// ===========================================================================
__global__ __launch_bounds__(512, 4) void winattn_proj(
    const u16* __restrict__ qkv,
    const u16* __restrict__ wpf,
    const float* __restrict__ bproj,
    float* __restrict__ out)
{
  __shared__ u16 lds[8][4096];   // per wave: V^T then O (swizzled, 128B rows)
  const int tid = threadIdx.x;
  const int l = tid & 63, w = tid >> 6;
  const int g = l >> 4,  ln = l & 15;
  const int gh = g >> 1, gl = g & 1;
  const long tokb = (long)blockIdx.x * 64;
  u16* vt = lds[w];
  const int h = w;

  // ---- V rows -> swizzled V^T in LDS (wave-private) ----
  {
    const int dg = l & 3, tg = l >> 2;
    uint4 vr[4][2];
    #pragma unroll
    for (int r = 0; r < 4; ++r){
      const char* vrow = (const char*)(qkv + (tokb + tg*4 + r) * 1536 + 1024 + h*64 + dg*16);
      vr[r][0] = *reinterpret_cast<const uint4*>(vrow);
      vr[r][1] = *reinterpret_cast<const uint4*>(vrow + 16);
    }
    #pragma unroll
    for (int dd = 0; dd < 16; ++dd){
      int d = dg*16 + dd;
      int sub = dd & 7, hi = dd >> 3;
      uint2 pk;
      pk.x = (u32)((const u16*)&vr[0][hi])[sub] | ((u32)((const u16*)&vr[1][hi])[sub] << 16);
      pk.y = (u32)((const u16*)&vr[2][hi])[sub] | ((u32)((const u16*)&vr[3][hi])[sub] << 16);
      *reinterpret_cast<uint2*>((char*)vt + d*128 + swz(d, tg*8)) = pk;
    }
  }

  f32x4 oacc[4][4];
  #pragma unroll
  for (int m = 0; m < 4; ++m)
    #pragma unroll
    for (int n = 0; n < 4; ++n) oacc[m][n] = (f32x4){0.f,0.f,0.f,0.f};

  const int lnA = ln + 32*gl;

  #pragma unroll
  for (int half = 0; half < 2; ++half){
    short8 qa[2][2];
    #pragma unroll
    for (int j = 0; j < 2; ++j){
      const char* qrow = (const char*)(qkv + (tokb + (half*2+j)*16 + ln) * 1536 + h*64 + g*8);
      qa[j][0] = *reinterpret_cast<const short8*>(qrow);
      qa[j][1] = *reinterpret_cast<const short8*>(qrow + 64);
    }
    f32x4 st[4][2];
    #pragma unroll
    for (int mk = 0; mk < 4; ++mk){
      st[mk][0] = (f32x4){0.f,0.f,0.f,0.f};
      st[mk][1] = (f32x4){0.f,0.f,0.f,0.f};
    }
    #pragma unroll
    for (int mk = 0; mk < 4; ++mk){
      const char* krow = (const char*)(qkv + (tokb + mk*16 + ln) * 1536 + 512 + h*64 + g*8);
      short8 kb0 = *reinterpret_cast<const short8*>(krow);
      short8 kb1 = *reinterpret_cast<const short8*>(krow + 64);
      #pragma unroll
      for (int j = 0; j < 2; ++j){
        st[mk][j] = __builtin_amdgcn_mfma_f32_16x16x32_bf16(kb0, qa[j][0], st[mk][j], 0, 0, 0);
        st[mk][j] = __builtin_amdgcn_mfma_f32_16x16x32_bf16(kb1, qa[j][1], st[mk][j], 0, 0, 0);
      }
    }
    u32 warr[4][2][2];
    #pragma unroll
    for (int j = 0; j < 2; ++j){
      float mx = -3.4e38f;
      #pragma unroll
      for (int mk = 0; mk < 4; ++mk)
        #pragma unroll
        for (int r = 0; r < 4; ++r) mx = fmaxf(mx, st[mk][j][r]);
      mx = fmaxf(mx, __shfl_xor(mx, 16, 64));
      mx = fmaxf(mx, __shfl_xor(mx, 32, 64));
      float s = 0.f;
      #pragma unroll
      for (int mk = 0; mk < 4; ++mk)
        #pragma unroll
        for (int r = 0; r < 4; ++r){
          float p = __expf((st[mk][j][r] - mx) * 0.125f);
          st[mk][j][r] = p; s += p;
        }
      s += __shfl_xor(s, 16, 64);
      s += __shfl_xor(s, 32, 64);
      float inv = 1.f / s;
      #pragma unroll
      for (int mk = 0; mk < 4; ++mk){
        warr[mk][j][0] = cvtpk(st[mk][j][0]*inv, st[mk][j][1]*inv);
        warr[mk][j][1] = cvtpk(st[mk][j][2]*inv, st[mk][j][3]*inv);
      }
    }
    __builtin_amdgcn_s_setprio(1);
    #pragma unroll
    for (int ks = 0; ks < 2; ++ks){
      short8 vb[4];
      #pragma unroll
      for (int n = 0; n < 4; ++n){
        int row = n*16 + ln;
        vb[n] = *reinterpret_cast<const short8*>((char*)vt + row*128 + swz(row, (ks*32 + g*8)*2));
      }
      #pragma unroll
      for (int mo = 0; mo < 2; ++mo){
        int m = half*2 + mo;
        u32 c0a = warr[2*ks  ][mo][0], c0b = warr[2*ks  ][mo][1];
        u32 c1a = warr[2*ks+1][mo][0], c1b = warr[2*ks+1][mo][1];
        u32 s0a = (u32)__shfl((int)c0a, lnA, 64);
        u32 s1a = (u32)__shfl((int)c1a, lnA, 64);
        u32 s0b = (u32)__shfl((int)c0b, lnA, 64);
        u32 s1b = (u32)__shfl((int)c1b, lnA, 64);
        u32 t0a = (u32)__shfl((int)c0a, lnA+16, 64);
        u32 t1a = (u32)__shfl((int)c1a, lnA+16, 64);
        u32 t0b = (u32)__shfl((int)c0b, lnA+16, 64);
        u32 t1b = (u32)__shfl((int)c1b, lnA+16, 64);
        union { u32 u[4]; short8 v; } pf;
        pf.u[0] = gh ? s1a : s0a;
        pf.u[1] = gh ? s1b : s0b;
        pf.u[2] = gh ? t1a : t0a;
        pf.u[3] = gh ? t1b : t0b;
        #pragma unroll
        for (int n = 0; n < 4; ++n)
          oacc[m][n] = __builtin_amdgcn_mfma_f32_16x16x32_bf16(pf.v, vb[n], oacc[m][n], 0, 0, 0);
      }
    }
    __builtin_amdgcn_s_setprio(0);
  }

  #pragma unroll
  for (int m = 0; m < 4; ++m)
    #pragma unroll
    for (int n = 0; n < 4; ++n){
      int d = n*16 + ln;
      #pragma unroll
      for (int r = 0; r < 4; ++r){
        int t = m*16 + g*4 + r;
        *reinterpret_cast<u16*>((char*)vt + t*128 + swz(t, d*2)) = f2bf(oacc[m][n][r]);
      }
    }

  __syncthreads();

  f32x4 acc[4][4];
  #pragma unroll
  for (int m = 0; m < 4; ++m)
    #pragma unroll
    for (int n = 0; n < 4; ++n) acc[m][n] = (f32x4){0.f,0.f,0.f,0.f};

  for (int hh = 0; hh < 8; ++hh){
    const char* obuf = (const char*)lds[hh];
    #pragma unroll
    for (int ks = 0; ks < 2; ++ks){
      short8 a[4], b[4];
      #pragma unroll
      for (int m = 0; m < 4; ++m){
        int row = m*16 + ln;
        a[m] = *reinterpret_cast<const short8*>(obuf + row*128 + swz(row, (ks*32 + g*8)*2));
      }
      #pragma unroll
      for (int n = 0; n < 4; ++n)
        b[n] = *reinterpret_cast<const short8*>(
            wpf + ((((long)w*8 + hh)*4 + n)*2 + ks)*512 + (long)l*8);
      __builtin_amdgcn_s_setprio(1);
      #pragma unroll
      for (int m = 0; m < 4; ++m)
        #pragma unroll
        for (int n = 0; n < 4; ++n)
          acc[m][n] = __builtin_amdgcn_mfma_f32_16x16x32_bf16(a[m], b[n], acc[m][n], 0, 0, 0);
      __builtin_amdgcn_s_setprio(0);
    }
  }

  #pragma unroll
  for (int n = 0; n < 4; ++n){
    int col = w*64 + n*16 + ln;
    float bias = bproj[col];
    #pragma unroll
    for (int m = 0; m < 4; ++m){
      #pragma unroll
      for (int r = 0; r < 4; ++r){
        int t = m*16 + g*4 + r;
        out[(tokb + t) * 512 + col] = acc[m][n][r] + bias;
      }
    }
  }
}

// ===========================================================================
// Fallback (round-1 fused kernel) for small ws_size
// ===========================================================================
__global__ void convert_weights(const float* __restrict__ wqkv,
                                const float* __restrict__ wproj,
                                u16* __restrict__ wqkvt,
                                u16* __restrict__ wprojt){
  int tid = blockIdx.x * 256 + threadIdx.x;
  union { u16 u[8]; uint4 v; } tmp;
  if (tid < 1536 * 64){
    int e  = tid >> 6;
    int kc = (tid & 63) << 3;
    #pragma unroll
    for (int i = 0; i < 8; ++i) tmp.u[i] = f2bf(wqkv[(long)(kc + i) * 1536 + e]);
    *reinterpret_cast<uint4*>(wqkvt + (long)e * 512 + kc) = tmp.v;
  } else {
    int t2 = tid - 1536 * 64;
    int c  = t2 >> 6;
    int kc = (t2 & 63) << 3;
    #pragma unroll
    for (int i = 0; i < 8; ++i) tmp.u[i] = f2bf(wproj[(long)(kc + i) * 512 + c]);
    *reinterpret_cast<uint4*>(wprojt + (long)c * 512 + kc) = tmp.v;
  }
}

__global__ __launch_bounds__(512, 2) void fused_winattn(
    const float* __restrict__ x,
    const u16*  __restrict__ wqkvt,
    const float* __restrict__ bqkv,
    const u16*  __restrict__ wprojt,
    const float* __restrict__ bproj,
    float* __restrict__ out)
{
  __shared__ u16 lds_x[64 * 512];
  __shared__ u16 lds_q[64 * 64];
  __shared__ u16 lds_k[64 * 64];
  __shared__ u16 lds_vt[64 * 64];
  __shared__ u16 lds_p[64 * 64];

  const int tid = threadIdx.x;
  const int l   = tid & 63;
  const int w   = tid >> 6;
  const int g   = l >> 4;
  const int ln  = l & 15;
  const long tokbase = (long)blockIdx.x * 64;

  {
    const float4* xv = reinterpret_cast<const float4*>(x + tokbase * 512);
    #pragma unroll
    for (int j = 0; j < 16; ++j){
      int i   = j * 512 + tid;
      int row = i >> 7;
      int c4  = i & 127;
      float4 v = xv[i];
      uint2 pk;
      pk.x = (u32)f2bf(v.x) | ((u32)f2bf(v.y) << 16);
      pk.y = (u32)f2bf(v.z) | ((u32)f2bf(v.w) << 16);
      int byte = row * 1024 + swz(row, c4 * 8);
      *reinterpret_cast<uint2*>(reinterpret_cast<char*>(lds_x) + byte) = pk;
    }
  }

  f32x4 oacc[4][4];
  #pragma unroll
  for (int m = 0; m < 4; ++m)
    #pragma unroll
    for (int n = 0; n < 4; ++n) oacc[m][n] = (f32x4){0.f, 0.f, 0.f, 0.f};

  const int mw   = w & 3;
  const int half = w >> 2;

  __syncthreads();

  for (int h = 0; h < 8; ++h){
    f32x4 qacc[6];
    #pragma unroll
    for (int j = 0; j < 6; ++j) qacc[j] = (f32x4){0.f, 0.f, 0.f, 0.f};
    int ebase[6];
    #pragma unroll
    for (int j = 0; j < 6; ++j){
      int nt = half * 6 + j;
      int sec = nt >> 2;
      ebase[j] = sec * 512 + h * 64 + (nt & 3) * 16;
    }
    const int arow = mw * 16 + ln;
    #pragma unroll
    for (int ks = 0; ks < 16; ++ks){
      short8 a = *reinterpret_cast<const short8*>(
          reinterpret_cast<const char*>(lds_x) + arow * 1024 + swz(arow, (ks * 32 + g * 8) * 2));
      #pragma unroll
      for (int j = 0; j < 6; ++j){
        short8 b = *reinterpret_cast<const short8*>(
            wqkvt + (long)(ebase[j] + ln) * 512 + ks * 32 + g * 8);
        qacc[j] = __builtin_amdgcn_mfma_f32_16x16x32_bf16(a, b, qacc[j], 0, 0, 0);
      }
    }
    #pragma unroll
    for (int j = 0; j < 6; ++j){
      int nt  = half * 6 + j;
      int sec = nt >> 2;
      float bias = bqkv[ebase[j] + ln];
      if (sec < 2){
        u16* dst = (sec == 0) ? lds_q : lds_k;
        int c = (nt & 3) * 16 + ln;
        #pragma unroll
        for (int r = 0; r < 4; ++r){
          int t = mw * 16 + g * 4 + r;
          int byte = t * 128 + swz(t, c * 2);
          *reinterpret_cast<u16*>(reinterpret_cast<char*>(dst) + byte) = f2bf(qacc[j][r] + bias);
        }
      } else {
        int d  = (nt & 3) * 16 + ln;
        int t0 = mw * 16 + g * 4;
        uint2 pk;
        pk.x = (u32)f2bf(qacc[j][0] + bias) | ((u32)f2bf(qacc[j][1] + bias) << 16);
        pk.y = (u32)f2bf(qacc[j][2] + bias) | ((u32)f2bf(qacc[j][3] + bias) << 16);
        int byte = d * 128 + swz(d, t0 * 2);
        *reinterpret_cast<uint2*>(reinterpret_cast<char*>(lds_vt) + byte) = pk;
      }
    }
    __syncthreads();

    if (w < 4){
      f32x4 sacc[4];
      #pragma unroll
      for (int jt = 0; jt < 4; ++jt) sacc[jt] = (f32x4){0.f, 0.f, 0.f, 0.f};
      #pragma unroll
      for (int ks = 0; ks < 2; ++ks){
        int qrow = w * 16 + ln;
        short8 a = *reinterpret_cast<const short8*>(
            reinterpret_cast<const char*>(lds_q) + qrow * 128 + swz(qrow, (ks * 32 + g * 8) * 2));
        #pragma unroll
        for (int jt = 0; jt < 4; ++jt){
          int krow = jt * 16 + ln;
          short8 b = *reinterpret_cast<const short8*>(
              reinterpret_cast<const char*>(lds_k) + krow * 128 + swz(krow, (ks * 32 + g * 8) * 2));
          sacc[jt] = __builtin_amdgcn_mfma_f32_16x16x32_bf16(a, b, sacc[jt], 0, 0, 0);
        }
      }
      #pragma unroll
      for (int r = 0; r < 4; ++r){
        float mx = fmaxf(fmaxf(sacc[0][r], sacc[1][r]), fmaxf(sacc[2][r], sacc[3][r]));
        mx = fmaxf(mx, __shfl_xor(mx, 1, 64));
        mx = fmaxf(mx, __shfl_xor(mx, 2, 64));
        mx = fmaxf(mx, __shfl_xor(mx, 4, 64));
        mx = fmaxf(mx, __shfl_xor(mx, 8, 64));
        float p[4], s = 0.f;
        #pragma unroll
        for (int jt = 0; jt < 4; ++jt){
          p[jt] = __expf((sacc[jt][r] - mx) * 0.125f);
          s += p[jt];
        }
        s += __shfl_xor(s, 1, 64);
        s += __shfl_xor(s, 2, 64);
        s += __shfl_xor(s, 4, 64);
        s += __shfl_xor(s, 8, 64);
        float inv = 1.f / s;
        int i = w * 16 + g * 4 + r;
        #pragma unroll
        for (int jt = 0; jt < 4; ++jt){
          int c = jt * 16 + ln;
          int byte = i * 128 + swz(i, c * 2);
          *reinterpret_cast<u16*>(reinterpret_cast<char*>(lds_p) + byte) = f2bf(p[jt] * inv);
        }
      }
    }
    __syncthreads();

    {
      int mc  = w & 3;
      int nc0 = (w >> 2) * 2;
      f32x4 oc[2];
      oc[0] = (f32x4){0.f, 0.f, 0.f, 0.f};
      oc[1] = (f32x4){0.f, 0.f, 0.f, 0.f};
      #pragma unroll
      for (int ks = 0; ks < 2; ++ks){
        int prow = mc * 16 + ln;
        short8 a = *reinterpret_cast<const short8*>(
            reinterpret_cast<const char*>(lds_p) + prow * 128 + swz(prow, (ks * 32 + g * 8) * 2));
        #pragma unroll
        for (int jj = 0; jj < 2; ++jj){
          int vrow = (nc0 + jj) * 16 + ln;
          short8 b = *reinterpret_cast<const short8*>(
              reinterpret_cast<const char*>(lds_vt) + vrow * 128 + swz(vrow, (ks * 32 + g * 8) * 2));
          oc[jj] = __builtin_amdgcn_mfma_f32_16x16x32_bf16(a, b, oc[jj], 0, 0, 0);
        }
      }
      #pragma unroll
      for (int jj = 0; jj < 2; ++jj){
        int d = (nc0 + jj) * 16 + ln;
        #pragma unroll
        for (int r = 0; r < 4; ++r){
          int t = mc * 16 + g * 4 + r;
          int byte = t * 128 + swz(t, d * 2);
          *reinterpret_cast<u16*>(reinterpret_cast<char*>(lds_q) + byte) = f2bf(oc[jj][r]);
        }
      }
    }
    __syncthreads();

    #pragma unroll
    for (int ks = 0; ks < 2; ++ks){
      short8 a[4];
      #pragma unroll
      for (int m = 0; m < 4; ++m){
        int row = m * 16 + ln;
        a[m] = *reinterpret_cast<const short8*>(
            reinterpret_cast<const char*>(lds_q) + row * 128 + swz(row, (ks * 32 + g * 8) * 2));
      }
      #pragma unroll
      for (int nt = 0; nt < 4; ++nt){
        int e = w * 64 + nt * 16 + ln;
        short8 b = *reinterpret_cast<const short8*>(
            wprojt + (long)e * 512 + h * 64 + ks * 32 + g * 8);
        #pragma unroll
        for (int m = 0; m < 4; ++m)
          oacc[m][nt] = __builtin_amdgcn_mfma_f32_16x16x32_bf16(a[m], b, oacc[m][nt], 0, 0, 0);
      }
    }
    __syncthreads();
  }

  #pragma unroll
  for (int nt = 0; nt < 4; ++nt){
    int col = w * 64 + nt * 16 + ln;
    float bias = bproj[col];
    #pragma unroll
    for (int m = 0; m < 4; ++m){
      #pragma unroll
      for (int r = 0; r < 4; ++r){
        int t = m * 16 + g * 4 + r;
        out[(tokbase + t) * 512 + col] = oacc[m][nt][r] + bias;
      }
    }
  }
}

extern "C" void kernel_launch(void* const* d_in, const int* in_sizes, int n_in,
                              void* d_out, int out_size, void* d_ws, size_t ws_size,
                              hipStream_t stream) {
  const float* x     = (const float*)d_in[0];
  const float* wqkv  = (const float*)d_in[1];
  const float* bqkv  = (const float*)d_in[2];
  const float* wproj = (const float*)d_in[3];
  const float* bproj = (const float*)d_in[4];
  float* out = (float*)d_out;

  // wqf 1.5M + wpf 0.5M + xbf 128M + qkv 384M = 514 MiB
  const size_t NEED = 538968064ULL;
  if (ws_size >= NEED){
    u16* wqf = (u16*)d_ws;
    u16* wpf = (u16*)((char*)d_ws + 1572864);
    u16* xbf = (u16*)((char*)d_ws + 2097152);
    u16* qkv = (u16*)((char*)d_ws + 136314880);
    convert_weights_frag<<<512, 256, 0, stream>>>(wqkv, wproj, wqf, wpf);
    convert_x<<<32768, 256, 0, stream>>>(x, xbf);
    qkv_gemm128<<<12288, 256, 0, stream>>>(xbf, wqf, bqkv, qkv);
    winattn_proj<<<2048, 512, 0, stream>>>(qkv, wpf, bproj, out);
  } else {
    u16* wqkvt  = (u16*)d_ws;
    u16* wprojt = wqkvt + 1536 * 512;
    convert_weights<<<512, 256, 0, stream>>>(wqkv, wproj, wqkvt, wprojt);
    fused_winattn<<<2048, 512, 0, stream>>>(x, wqkvt, bqkv, wprojt, bproj, out);
  }
}